// Round 4
// baseline (77.684 us; speedup 1.0000x reference)
//
#include <hip/hip_runtime.h>
#include <math.h>

#define NEGS 20
#define DIMS 128
#define REGC 1e-6f
#define LPR  16            // lanes per row
#define RPW  4             // rows per wave = 64/LPR

__device__ __forceinline__ float log_sigmoid(float x) {
    // stable: logsig(x) = min(x,0) - log(1+exp(-|x|))
    float t = __expf(-fabsf(x));
    float l = -__logf(1.f + t);
    return x >= 0.f ? l : x + l;
}

__device__ __forceinline__ float dot4(float4 a, float4 b) {
    return a.x*b.x + a.y*b.y + a.z*b.z + a.w*b.w;
}

// One wave per block. All 46 row-chunk loads issued into independent registers
// BEFORE any consumption -> max memory-level parallelism per wave. No
// launch-bounds VGPR cap: we trade occupancy for in-flight loads.
__global__ void sg_loss_kernel(
    const float* __restrict__ u_emb,
    const float* __restrict__ v_emb,
    const float* __restrict__ pretrained,
    const int* __restrict__ u_pos,
    const int* __restrict__ v_pos,
    const int* __restrict__ v_neg,
    float* __restrict__ out,
    int batch)
{
    const int lane = threadIdx.x;           // block == one wave (64)
    const int l    = lane & (LPR - 1);      // lane within 16-lane row group
    const int g    = lane >> 4;             // row group within wave (0..3)

    const int  b     = blockIdx.x * RPW + g;
    const bool valid = (b < batch);
    const int  ib    = valid ? b : 0;

    const int iu = u_pos[ib];
    const int iv = v_pos[ib];

    int negidx[NEGS];
    #pragma unroll
    for (int n = 0; n < NEGS; ++n) negidx[n] = v_neg[ib * NEGS + n];

    const float4* up = (const float4*)(u_emb      + (size_t)iu * DIMS);
    const float4* vp = (const float4*)(v_emb      + (size_t)iv * DIMS);
    const float4* pp = (const float4*)(pretrained + (size_t)iu * DIMS);

    // ---- issue ALL loads first (46 x 16B per lane in flight) ----
    const float4 u0 = up[l], u1 = up[l + 16];
    const float4 v0 = vp[l], v1 = vp[l + 16];
    const float4 p0 = pp[l], p1 = pp[l + 16];
    float4 a[NEGS], c[NEGS];
    #pragma unroll
    for (int n = 0; n < NEGS; ++n) {
        const float4* np = (const float4*)(v_emb + (size_t)negidx[n] * DIMS);
        a[n] = np[l];
        c[n] = np[l + 16];
    }

    // ---- consume (compiler drains vmcnt progressively, oldest first) ----
    float part[NEGS + 1];
    part[0] = dot4(u0, v0) + dot4(u1, v1);
    #pragma unroll
    for (int n = 0; n < NEGS; ++n) part[n + 1] = dot4(u0, a[n]) + dot4(u1, c[n]);

    float rp = fabsf(u0.x - p0.x) + fabsf(u0.y - p0.y)
             + fabsf(u0.z - p0.z) + fabsf(u0.w - p0.w)
             + fabsf(u1.x - p1.x) + fabsf(u1.y - p1.y)
             + fabsf(u1.z - p1.z) + fabsf(u1.w - p1.w);

    // 4-stage butterfly within each 16-lane group (21 parts + rp, 4 rows/wave)
    #pragma unroll
    for (int off = 8; off > 0; off >>= 1) {
        #pragma unroll
        for (int k = 0; k <= NEGS; ++k) part[k] += __shfl_xor(part[k], off, 16);
        rp += __shfl_xor(rp, off, 16);
    }

    // group-uniform nonlinearity: 1 wave instr covers 4 rows
    float acc = log_sigmoid(part[0]);
    #pragma unroll
    for (int n = 0; n < NEGS; ++n) acc += log_sigmoid(-part[n + 1]);

    if (!valid) { acc = 0.f; rp = 0.f; }
    float s1 = acc;
    float s2 = rp;

    // combine the 4 groups within the wave (values group-uniform)
    s1 += __shfl_xor(s1, 16, 64);  s2 += __shfl_xor(s2, 16, 64);
    s1 += __shfl_xor(s1, 32, 64);  s2 += __shfl_xor(s2, 32, 64);

    if (lane == 0) {
        // out = -(S1)/B - REG*S2   (reg_total broadcast over B cancels the /B)
        const float contrib = -(s1 / (float)batch) - REGC * s2;
        atomicAdd(out, contrib);
    }
}

extern "C" void kernel_launch(void* const* d_in, const int* in_sizes, int n_in,
                              void* d_out, int out_size, void* d_ws, size_t ws_size,
                              hipStream_t stream) {
    const float* u_emb      = (const float*)d_in[0];
    const float* v_emb      = (const float*)d_in[1];
    const float* pretrained = (const float*)d_in[2];
    const int*   u_pos      = (const int*)d_in[3];
    const int*   v_pos      = (const int*)d_in[4];
    const int*   v_neg      = (const int*)d_in[5];
    float* out = (float*)d_out;
    const int batch = in_sizes[3];

    hipMemsetAsync(out, 0, sizeof(float), stream);

    dim3 block(64);                              // one wave per block
    int blocks = (batch + RPW - 1) / RPW;        // 4096
    sg_loss_kernel<<<dim3(blocks), block, 0, stream>>>(u_emb, v_emb, pretrained,
                                                       u_pos, v_pos, v_neg, out, batch);
}

// Round 5
// 47.078 us; speedup vs baseline: 1.6501x; 1.6501x over previous
//
#include <hip/hip_runtime.h>
#include <math.h>

#define NEGS 20
#define DIMS 128
#define REGC 1e-6f
#define LPR  16            // lanes per row
#define RPW  4             // rows per wave = 64/LPR

__device__ __forceinline__ float log_sigmoid(float x) {
    // stable: logsig(x) = min(x,0) - log(1+exp(-|x|))
    float t = __expf(-fabsf(x));
    float l = -__logf(1.f + t);
    return x >= 0.f ? l : x + l;
}

__device__ __forceinline__ float dot4(float4 a, float4 b) {
    return a.x*b.x + a.y*b.y + a.z*b.z + a.w*b.w;
}

// R1 structure + forced load clustering: issue ALL 46 row-chunk loads, then a
// sched_barrier(0) so the scheduler cannot sink loads into the consumption
// code. This is the clean test of "per-wave MLP is the limiter" vs
// "2 TB/s is the random-row HBM wall".
__global__ __launch_bounds__(256) void sg_loss_kernel(
    const float* __restrict__ u_emb,
    const float* __restrict__ v_emb,
    const float* __restrict__ pretrained,
    const int* __restrict__ u_pos,
    const int* __restrict__ v_pos,
    const int* __restrict__ v_neg,
    float* __restrict__ out,
    int batch)
{
    const int lane = threadIdx.x & 63;
    const int l    = lane & (LPR - 1);     // lane within 16-lane row group
    const int g    = lane >> 4;            // row group within wave (0..3)
    const int wib  = threadIdx.x >> 6;
    const int wpb  = blockDim.x >> 6;
    const int gwave = blockIdx.x * wpb + wib;

    const int  b     = gwave * RPW + g;
    const bool valid = (b < batch);
    const int  ib    = valid ? b : 0;

    const int iu = u_pos[ib];
    const int iv = v_pos[ib];

    int negidx[NEGS];
    #pragma unroll
    for (int n = 0; n < NEGS; ++n) negidx[n] = v_neg[ib * NEGS + n];

    const float4* up = (const float4*)(u_emb      + (size_t)iu * DIMS);
    const float4* vp = (const float4*)(v_emb      + (size_t)iv * DIMS);
    const float4* pp = (const float4*)(pretrained + (size_t)iu * DIMS);

    // ---- issue ALL loads (46 x 16B per lane) ----
    const float4 u0 = up[l], u1 = up[l + 16];
    const float4 v0 = vp[l], v1 = vp[l + 16];
    const float4 p0 = pp[l], p1 = pp[l + 16];
    float4 a[NEGS], c[NEGS];
    #pragma unroll
    for (int n = 0; n < NEGS; ++n) {
        const float4* np = (const float4*)(v_emb + (size_t)negidx[n] * DIMS);
        a[n] = np[l];
        c[n] = np[l + 16];
    }

    // hard fence: no instruction (incl. these loads) may be moved across
    __builtin_amdgcn_sched_barrier(0);

    // ---- consume (compiler drains vmcnt progressively, oldest first) ----
    float part[NEGS + 1];
    part[0] = dot4(u0, v0) + dot4(u1, v1);
    #pragma unroll
    for (int n = 0; n < NEGS; ++n) part[n + 1] = dot4(u0, a[n]) + dot4(u1, c[n]);

    float rp = fabsf(u0.x - p0.x) + fabsf(u0.y - p0.y)
             + fabsf(u0.z - p0.z) + fabsf(u0.w - p0.w)
             + fabsf(u1.x - p1.x) + fabsf(u1.y - p1.y)
             + fabsf(u1.z - p1.z) + fabsf(u1.w - p1.w);

    // 4-stage butterfly within each 16-lane group (21 parts + rp, 4 rows/wave)
    #pragma unroll
    for (int off = 8; off > 0; off >>= 1) {
        #pragma unroll
        for (int k = 0; k <= NEGS; ++k) part[k] += __shfl_xor(part[k], off, 16);
        rp += __shfl_xor(rp, off, 16);
    }

    // group-uniform nonlinearity: 1 wave instr covers 4 rows
    float acc = log_sigmoid(part[0]);
    #pragma unroll
    for (int n = 0; n < NEGS; ++n) acc += log_sigmoid(-part[n + 1]);

    if (!valid) { acc = 0.f; rp = 0.f; }
    float s1 = acc;
    float s2 = rp;

    // combine the 4 groups within the wave (values group-uniform)
    s1 += __shfl_xor(s1, 16, 64);  s2 += __shfl_xor(s2, 16, 64);
    s1 += __shfl_xor(s1, 32, 64);  s2 += __shfl_xor(s2, 32, 64);

    __shared__ float ls1[4], ls2[4];
    if (lane == 0) { ls1[wib] = s1; ls2[wib] = s2; }
    __syncthreads();
    if (threadIdx.x == 0) {
        float t1 = 0.f, t2 = 0.f;
        for (int w = 0; w < wpb; ++w) { t1 += ls1[w]; t2 += ls2[w]; }
        // out = -(S1)/B - REG*S2   (reg_total broadcast over B cancels the /B)
        const float contrib = -(t1 / (float)batch) - REGC * t2;
        atomicAdd(out, contrib);
    }
}

extern "C" void kernel_launch(void* const* d_in, const int* in_sizes, int n_in,
                              void* d_out, int out_size, void* d_ws, size_t ws_size,
                              hipStream_t stream) {
    const float* u_emb      = (const float*)d_in[0];
    const float* v_emb      = (const float*)d_in[1];
    const float* pretrained = (const float*)d_in[2];
    const int*   u_pos      = (const int*)d_in[3];
    const int*   v_pos      = (const int*)d_in[4];
    const int*   v_neg      = (const int*)d_in[5];
    float* out = (float*)d_out;
    const int batch = in_sizes[3];

    hipMemsetAsync(out, 0, sizeof(float), stream);

    dim3 block(256);
    int nwaves = (batch + RPW - 1) / RPW;    // 4096
    int blocks = (nwaves + 3) / 4;           // 1024
    sg_loss_kernel<<<dim3(blocks), block, 0, stream>>>(u_emb, v_emb, pretrained,
                                                       u_pos, v_pos, v_neg, out, batch);
}